// Round 1
// baseline (199.522 us; speedup 1.0000x reference)
//
#include <hip/hip_runtime.h>
#include <hip/hip_bf16.h>

// Problem constants
#define B_ 4
#define C_ 512
#define N_ 2048
#define H_ 8
#define D_ 64
#define O3_ 1536   // 3*C

typedef __bf16 bf16x8 __attribute__((ext_vector_type(8)));
typedef float f32x4 __attribute__((ext_vector_type(4)));
typedef unsigned short ushort_t;

__device__ inline ushort_t f2b(float f) {
    __hip_bfloat16 h = __float2bfloat16(f);
    return *reinterpret_cast<ushort_t*>(&h);
}

// ---------------------------------------------------------------------------
// Kernel 0: convert weights fp32 -> bf16
// ---------------------------------------------------------------------------
__global__ __launch_bounds__(256) void k_cvt(const float* __restrict__ wqkv,
                                             const float* __restrict__ wout,
                                             ushort_t* __restrict__ wqkv_b,
                                             ushort_t* __restrict__ wout_b) {
    int i = blockIdx.x * 256 + threadIdx.x;
    if (i < O3_ * C_) wqkv_b[i] = f2b(wqkv[i]);
    if (i < C_ * C_)  wout_b[i] = f2b(wout[i]);
}

// ---------------------------------------------------------------------------
// Kernel 1: channel LayerNorm (over c) + transpose -> xnT[b][n][c] bf16
// block = 256 threads, handles (b, 32 columns of n)
// ---------------------------------------------------------------------------
__global__ __launch_bounds__(256) void k_ln(const float* __restrict__ x,
                                            const float* __restrict__ g,
                                            ushort_t* __restrict__ xnT) {
    int bid = blockIdx.x;
    int b  = bid >> 6;            // 64 j-tiles per batch
    int j0 = (bid & 63) * 32;
    int t  = threadIdx.x;

    __shared__ float s_red[8][32];
    __shared__ float s_red2[8][32];
    __shared__ float s_mean[32], s_rstd[32];
    __shared__ float s_g[C_];
    __shared__ __align__(16) ushort_t s_t[32][C_ + 2];  // +2 pad: stride 257 words

    for (int i = t; i < C_; i += 256) s_g[i] = g[i];

    int jl = t & 31, cg = t >> 5;
    const float* xb = x + (size_t)b * C_ * N_;

    // phase 1: partial sums over 64 channels per group, coalesced along j
    float sum = 0.f, sq = 0.f;
#pragma unroll 4
    for (int c = cg * 64; c < cg * 64 + 64; ++c) {
        float v = xb[(size_t)c * N_ + j0 + jl];
        sum += v; sq += v * v;
    }
    s_red[cg][jl] = sum; s_red2[cg][jl] = sq;
    __syncthreads();
    if (t < 32) {
        float s = 0.f, q = 0.f;
#pragma unroll
        for (int i = 0; i < 8; ++i) { s += s_red[i][t]; q += s_red2[i][t]; }
        float mean = s * (1.0f / C_);
        float var  = q * (1.0f / C_) - mean * mean;
        s_mean[t] = mean;
        s_rstd[t] = rsqrtf(var + 1e-5f);
    }
    __syncthreads();

    // phase 2: normalize, write bf16 into LDS transpose tile [j][c]
    for (int it = 0; it < 64; ++it) {
        int c = it * 8 + cg;
        float v  = xb[(size_t)c * N_ + j0 + jl];
        float xn = (v - s_mean[jl]) * s_rstd[jl] * s_g[c];
        s_t[jl][c] = f2b(xn);
    }
    __syncthreads();

    // phase 3: coalesced write of xnT rows (c contiguous)
    for (int jr = 0; jr < 32; ++jr) {
        unsigned val = *reinterpret_cast<const unsigned*>(&s_t[jr][t * 2]);
        *reinterpret_cast<unsigned*>(
            &xnT[((size_t)(b * N_ + j0 + jr)) * C_ + t * 2]) = val;
    }
}

// ---------------------------------------------------------------------------
// GEMM: C[o][j] = sum_c A[o][c] * BT[b][j][c]   (A,B bf16, acc fp32)
// MODE 0: A=w_qkv (M=1536) -> split epilogue into qT/kT/v (q scaled 0.125)
// MODE 1: A=w_out (M=512)  -> out fp32 + b_out
// tile 128x128, BK=64, 256 threads (4 waves, 2x2), padded LDS (+8 bf16)
// ---------------------------------------------------------------------------
template <int MODE>
__global__ __launch_bounds__(256) void k_gemm(const ushort_t* __restrict__ A,
                                              const ushort_t* __restrict__ Bt,
                                              ushort_t* __restrict__ qT,
                                              ushort_t* __restrict__ kT,
                                              ushort_t* __restrict__ vv,
                                              float* __restrict__ out,
                                              const float* __restrict__ b_out) {
    constexpr int M = (MODE == 0) ? O3_ : C_;
    constexpr int K = C_;
    constexpr int NMT = M / 128;

    int bid = blockIdx.x;
    int b   = bid / (NMT * 16);
    int rem = bid % (NMT * 16);
    int mt0 = (rem / 16) * 128;
    int nt0 = (rem % 16) * 128;

    int t = threadIdx.x;
    int w = t >> 6, lane = t & 63;
    int wm = (w >> 1) * 64, wn = (w & 1) * 64;

    __shared__ __align__(16) ushort_t sA[128][72];
    __shared__ __align__(16) ushort_t sB[128][72];

    const ushort_t* Bb = Bt + (size_t)b * N_ * K;

    f32x4 acc[4][4] = {};

    for (int k0 = 0; k0 < K; k0 += 64) {
        __syncthreads();
        // stage A and B tiles: 128 rows x 64 cols each, 16B chunks
#pragma unroll
        for (int it = 0; it < 4; ++it) {
            int chunk = it * 256 + t;
            int row = chunk >> 3, cc = (chunk & 7) * 8;
            uint4 va = *reinterpret_cast<const uint4*>(
                &A[(size_t)(mt0 + row) * K + k0 + cc]);
            *reinterpret_cast<uint4*>(&sA[row][cc]) = va;
            uint4 vb = *reinterpret_cast<const uint4*>(
                &Bb[(size_t)(nt0 + row) * K + k0 + cc]);
            *reinterpret_cast<uint4*>(&sB[row][cc]) = vb;
        }
        __syncthreads();
#pragma unroll
        for (int kk = 0; kk < 64; kk += 32) {
            bf16x8 af[4], bfr[4];
#pragma unroll
            for (int mt = 0; mt < 4; ++mt)
                af[mt] = *reinterpret_cast<const bf16x8*>(
                    &sA[wm + mt * 16 + (lane & 15)][kk + (lane >> 4) * 8]);
#pragma unroll
            for (int nt = 0; nt < 4; ++nt)
                bfr[nt] = *reinterpret_cast<const bf16x8*>(
                    &sB[wn + nt * 16 + (lane & 15)][kk + (lane >> 4) * 8]);
#pragma unroll
            for (int mt = 0; mt < 4; ++mt)
#pragma unroll
                for (int nt = 0; nt < 4; ++nt)
                    acc[mt][nt] = __builtin_amdgcn_mfma_f32_16x16x32_bf16(
                        af[mt], bfr[nt], acc[mt][nt], 0, 0, 0);
        }
    }

    // epilogue: C row m = (lane>>4)*4 + r, col j = lane&15 within 16x16 tile
#pragma unroll
    for (int mt = 0; mt < 4; ++mt)
#pragma unroll
        for (int nt = 0; nt < 4; ++nt)
#pragma unroll
            for (int r = 0; r < 4; ++r) {
                int m = mt0 + wm + mt * 16 + (lane >> 4) * 4 + r;
                int j = nt0 + wn + nt * 16 + (lane & 15);
                float val = acc[mt][nt][r];
                if constexpr (MODE == 0) {
                    if (m < 512) {
                        qT[(((size_t)(b * H_ + (m >> 6)) * N_) + j) * D_ + (m & 63)] =
                            f2b(val * 0.125f);
                    } else if (m < 1024) {
                        int mm = m - 512;
                        kT[(((size_t)(b * H_ + (mm >> 6)) * N_) + j) * D_ + (mm & 63)] =
                            f2b(val);
                    } else {
                        int mm = m - 1024;
                        vv[(((size_t)(b * H_ + (mm >> 6)) * D_) + (mm & 63)) * N_ + j] =
                            f2b(val);
                    }
                } else {
                    out[((size_t)(b * C_ + m)) * N_ + j] = val + b_out[m];
                }
            }
}

// ---------------------------------------------------------------------------
// Flash attention: per (b,h,64-row Q tile), iterate 64-wide KV tiles.
// 4 waves, each owns 16 Q rows exclusively (online softmax is wave-local).
// qT/kT: [b][h][n][d] bf16 (q pre-scaled); v: [b][h][d][n]; out: attnT[b][n][c]
// ---------------------------------------------------------------------------
__global__ __launch_bounds__(256) void k_attn(const ushort_t* __restrict__ qT,
                                              const ushort_t* __restrict__ kT,
                                              const ushort_t* __restrict__ vv,
                                              ushort_t* __restrict__ attnT) {
    int bid  = blockIdx.x;
    int it64 = bid & 31;
    int h    = (bid >> 5) & 7;
    int b    = bid >> 8;
    int i0   = it64 * 64;
    int t = threadIdx.x, w = t >> 6, lane = t & 63;

    __shared__ __align__(16) ushort_t sQ[64][72];
    __shared__ __align__(16) ushort_t sK[64][72];
    __shared__ __align__(16) ushort_t sV[64][72];  // [d][j]
    __shared__ __align__(16) ushort_t sP[64][72];

    const ushort_t* qb = qT + ((size_t)(b * H_ + h)) * N_ * D_;
    const ushort_t* kb = kT + ((size_t)(b * H_ + h)) * N_ * D_;
    const ushort_t* vb = vv + ((size_t)(b * H_ + h)) * D_ * N_;

    // load Q tile (64x64)
#pragma unroll
    for (int it = 0; it < 2; ++it) {
        int chunk = it * 256 + t;
        int row = chunk >> 3, cc = (chunk & 7) * 8;
        *reinterpret_cast<uint4*>(&sQ[row][cc]) =
            *reinterpret_cast<const uint4*>(&qb[(size_t)(i0 + row) * D_ + cc]);
    }

    f32x4 oacc[4] = {};
    float m_run[4], l_run[4];
#pragma unroll
    for (int r = 0; r < 4; ++r) { m_run[r] = -1e30f; l_run[r] = 0.f; }

    for (int jt = 0; jt < N_ / 64; ++jt) {
        int j0 = jt * 64;
        __syncthreads();
#pragma unroll
        for (int it = 0; it < 2; ++it) {
            int chunk = it * 256 + t;
            int row = chunk >> 3, cc = (chunk & 7) * 8;
            *reinterpret_cast<uint4*>(&sK[row][cc]) =
                *reinterpret_cast<const uint4*>(&kb[(size_t)(j0 + row) * D_ + cc]);
            *reinterpret_cast<uint4*>(&sV[row][cc]) =
                *reinterpret_cast<const uint4*>(&vb[(size_t)row * N_ + j0 + cc]);
        }
        __syncthreads();

        // S = Q K^T : this wave's 16 rows x 64 cols
        f32x4 sacc[4] = {};
#pragma unroll
        for (int kk = 0; kk < 64; kk += 32) {
            bf16x8 aq = *reinterpret_cast<const bf16x8*>(
                &sQ[w * 16 + (lane & 15)][kk + (lane >> 4) * 8]);
#pragma unroll
            for (int nt = 0; nt < 4; ++nt) {
                bf16x8 bk = *reinterpret_cast<const bf16x8*>(
                    &sK[nt * 16 + (lane & 15)][kk + (lane >> 4) * 8]);
                sacc[nt] = __builtin_amdgcn_mfma_f32_16x16x32_bf16(
                    aq, bk, sacc[nt], 0, 0, 0);
            }
        }

        // online softmax: 4 rows per lane (reg r); reduce across 16 lanes
        float pv[4][4];
#pragma unroll
        for (int r = 0; r < 4; ++r) {
            float tm = fmaxf(fmaxf(sacc[0][r], sacc[1][r]),
                             fmaxf(sacc[2][r], sacc[3][r]));
#pragma unroll
            for (int mk = 1; mk < 16; mk <<= 1) tm = fmaxf(tm, __shfl_xor(tm, mk));
            float mn = fmaxf(m_run[r], tm);
            float sc = __expf(m_run[r] - mn);
            m_run[r] = mn;
            float rs = 0.f;
#pragma unroll
            for (int nt = 0; nt < 4; ++nt) {
                float p = __expf(sacc[nt][r] - mn);
                pv[nt][r] = p;
                rs += p;
            }
#pragma unroll
            for (int mk = 1; mk < 16; mk <<= 1) rs += __shfl_xor(rs, mk);
            l_run[r] = l_run[r] * sc + rs;
#pragma unroll
            for (int dt = 0; dt < 4; ++dt) oacc[dt][r] *= sc;
        }

        // write P strip (wave-exclusive rows -> no barrier needed)
#pragma unroll
        for (int nt = 0; nt < 4; ++nt)
#pragma unroll
            for (int r = 0; r < 4; ++r)
                sP[w * 16 + (lane >> 4) * 4 + r][nt * 16 + (lane & 15)] =
                    f2b(pv[nt][r]);

        // O += P V : A from own P rows, B from sV[d][j]
#pragma unroll
        for (int kk = 0; kk < 64; kk += 32) {
            bf16x8 ap = *reinterpret_cast<const bf16x8*>(
                &sP[w * 16 + (lane & 15)][kk + (lane >> 4) * 8]);
#pragma unroll
            for (int dt = 0; dt < 4; ++dt) {
                bf16x8 bv = *reinterpret_cast<const bf16x8*>(
                    &sV[dt * 16 + (lane & 15)][kk + (lane >> 4) * 8]);
                oacc[dt] = __builtin_amdgcn_mfma_f32_16x16x32_bf16(
                    ap, bv, oacc[dt], 0, 0, 0);
            }
        }
    }

    // normalize and write attnT[b][i][h*64+d]
    ushort_t* ob = attnT + ((size_t)b * N_ + i0) * C_ + h * D_;
#pragma unroll
    for (int dt = 0; dt < 4; ++dt)
#pragma unroll
        for (int r = 0; r < 4; ++r) {
            int i = w * 16 + (lane >> 4) * 4 + r;
            float val = oacc[dt][r] / l_run[r];
            ob[(size_t)i * C_ + dt * 16 + (lane & 15)] = f2b(val);
        }
}

// ---------------------------------------------------------------------------
// Launch
// ---------------------------------------------------------------------------
extern "C" void kernel_launch(void* const* d_in, const int* in_sizes, int n_in,
                              void* d_out, int out_size, void* d_ws, size_t ws_size,
                              hipStream_t stream) {
    const float* x    = (const float*)d_in[0];
    const float* g    = (const float*)d_in[1];
    const float* wqkv = (const float*)d_in[2];
    const float* wout = (const float*)d_in[3];
    const float* bout = (const float*)d_in[4];
    float* out = (float*)d_out;

    char* ws = (char*)d_ws;
    // each of xnT/qT/kT/v/attnT: 4*2048*512*2 = 8 MiB
    ushort_t* xnT    = (ushort_t*)(ws);
    ushort_t* qT     = (ushort_t*)(ws + (size_t)8  * 1024 * 1024);
    ushort_t* kT     = (ushort_t*)(ws + (size_t)16 * 1024 * 1024);
    ushort_t* vv     = (ushort_t*)(ws + (size_t)24 * 1024 * 1024);
    ushort_t* attnT  = (ushort_t*)(ws + (size_t)32 * 1024 * 1024);
    ushort_t* wqkv_b = (ushort_t*)(ws + (size_t)40 * 1024 * 1024);
    ushort_t* wout_b = (ushort_t*)(ws + (size_t)42 * 1024 * 1024);
    // total ws use: ~42.5 MiB

    k_cvt<<<dim3((O3_ * C_ + 255) / 256), dim3(256), 0, stream>>>(
        wqkv, wout, wqkv_b, wout_b);
    k_ln<<<dim3(B_ * (N_ / 32)), dim3(256), 0, stream>>>(x, g, xnT);
    k_gemm<0><<<dim3(B_ * (O3_ / 128) * (N_ / 128)), dim3(256), 0, stream>>>(
        wqkv_b, xnT, qT, kT, vv, nullptr, nullptr);
    k_attn<<<dim3(B_ * H_ * (N_ / 64)), dim3(256), 0, stream>>>(qT, kT, vv, attnT);
    k_gemm<1><<<dim3(B_ * (C_ / 128) * (N_ / 128)), dim3(256), 0, stream>>>(
        wout_b, attnT, nullptr, nullptr, nullptr, out, bout);
}

// Round 2
// 197.424 us; speedup vs baseline: 1.0106x; 1.0106x over previous
//
#include <hip/hip_runtime.h>
#include <hip/hip_bf16.h>

// Problem constants
#define B_ 4
#define C_ 512
#define N_ 2048
#define H_ 8
#define D_ 64
#define O3_ 1536   // 3*C

typedef __bf16 bf16x8 __attribute__((ext_vector_type(8)));
typedef float f32x4 __attribute__((ext_vector_type(4)));
typedef unsigned short ushort_t;

// q pre-scale: d^-0.5 (=0.125) * log2(e) so softmax uses exp2 directly
#define QSCALE 0.1803368801111137f

__device__ inline ushort_t f2b(float f) {
    __hip_bfloat16 h = __float2bfloat16(f);
    return *reinterpret_cast<ushort_t*>(&h);
}

// ---------------------------------------------------------------------------
// Kernel 0: convert weights fp32 -> bf16
// ---------------------------------------------------------------------------
__global__ __launch_bounds__(256) void k_cvt(const float* __restrict__ wqkv,
                                             const float* __restrict__ wout,
                                             ushort_t* __restrict__ wqkv_b,
                                             ushort_t* __restrict__ wout_b) {
    int i = blockIdx.x * 256 + threadIdx.x;
    if (i < O3_ * C_) wqkv_b[i] = f2b(wqkv[i]);
    if (i < C_ * C_)  wout_b[i] = f2b(wout[i]);
}

// ---------------------------------------------------------------------------
// Kernel 1: channel LayerNorm (over c) + transpose -> xnT[b][n][c] bf16
// ---------------------------------------------------------------------------
__global__ __launch_bounds__(256) void k_ln(const float* __restrict__ x,
                                            const float* __restrict__ g,
                                            ushort_t* __restrict__ xnT) {
    int bid = blockIdx.x;
    int b  = bid >> 6;            // 64 j-tiles per batch
    int j0 = (bid & 63) * 32;
    int t  = threadIdx.x;

    __shared__ float s_red[8][32];
    __shared__ float s_red2[8][32];
    __shared__ float s_mean[32], s_rstd[32];
    __shared__ float s_g[C_];
    __shared__ __align__(16) ushort_t s_t[32][C_ + 2];

    for (int i = t; i < C_; i += 256) s_g[i] = g[i];

    int jl = t & 31, cg = t >> 5;
    const float* xb = x + (size_t)b * C_ * N_;

    float sum = 0.f, sq = 0.f;
#pragma unroll 4
    for (int c = cg * 64; c < cg * 64 + 64; ++c) {
        float v = xb[(size_t)c * N_ + j0 + jl];
        sum += v; sq += v * v;
    }
    s_red[cg][jl] = sum; s_red2[cg][jl] = sq;
    __syncthreads();
    if (t < 32) {
        float s = 0.f, q = 0.f;
#pragma unroll
        for (int i = 0; i < 8; ++i) { s += s_red[i][t]; q += s_red2[i][t]; }
        float mean = s * (1.0f / C_);
        float var  = q * (1.0f / C_) - mean * mean;
        s_mean[t] = mean;
        s_rstd[t] = rsqrtf(var + 1e-5f);
    }
    __syncthreads();

    for (int it = 0; it < 64; ++it) {
        int c = it * 8 + cg;
        float v  = xb[(size_t)c * N_ + j0 + jl];
        float xn = (v - s_mean[jl]) * s_rstd[jl] * s_g[c];
        s_t[jl][c] = f2b(xn);
    }
    __syncthreads();

    for (int jr = 0; jr < 32; ++jr) {
        unsigned val = *reinterpret_cast<const unsigned*>(&s_t[jr][t * 2]);
        *reinterpret_cast<unsigned*>(
            &xnT[((size_t)(b * N_ + j0 + jr)) * C_ + t * 2]) = val;
    }
}

// ---------------------------------------------------------------------------
// GEMM: C[o][j] = sum_c A[o][c] * BT[b][j][c]   (A,B bf16, acc fp32)
// MODE 0: -> qT (scaled QSCALE) / kT / v ;  MODE 1: -> out fp32 + b_out
// ---------------------------------------------------------------------------
template <int MODE>
__global__ __launch_bounds__(256) void k_gemm(const ushort_t* __restrict__ A,
                                              const ushort_t* __restrict__ Bt,
                                              ushort_t* __restrict__ qT,
                                              ushort_t* __restrict__ kT,
                                              ushort_t* __restrict__ vv,
                                              float* __restrict__ out,
                                              const float* __restrict__ b_out) {
    constexpr int M = (MODE == 0) ? O3_ : C_;
    constexpr int K = C_;
    constexpr int NMT = M / 128;

    int bid = blockIdx.x;
    int b   = bid / (NMT * 16);
    int rem = bid % (NMT * 16);
    int mt0 = (rem / 16) * 128;
    int nt0 = (rem % 16) * 128;

    int t = threadIdx.x;
    int w = t >> 6, lane = t & 63;
    int wm = (w >> 1) * 64, wn = (w & 1) * 64;

    __shared__ __align__(16) ushort_t sA[128][72];
    __shared__ __align__(16) ushort_t sB[128][72];

    const ushort_t* Bb = Bt + (size_t)b * N_ * K;

    f32x4 acc[4][4] = {};

    for (int k0 = 0; k0 < K; k0 += 64) {
        __syncthreads();
#pragma unroll
        for (int it = 0; it < 4; ++it) {
            int chunk = it * 256 + t;
            int row = chunk >> 3, cc = (chunk & 7) * 8;
            uint4 va = *reinterpret_cast<const uint4*>(
                &A[(size_t)(mt0 + row) * K + k0 + cc]);
            *reinterpret_cast<uint4*>(&sA[row][cc]) = va;
            uint4 vb = *reinterpret_cast<const uint4*>(
                &Bb[(size_t)(nt0 + row) * K + k0 + cc]);
            *reinterpret_cast<uint4*>(&sB[row][cc]) = vb;
        }
        __syncthreads();
#pragma unroll
        for (int kk = 0; kk < 64; kk += 32) {
            bf16x8 af[4], bfr[4];
#pragma unroll
            for (int mt = 0; mt < 4; ++mt)
                af[mt] = *reinterpret_cast<const bf16x8*>(
                    &sA[wm + mt * 16 + (lane & 15)][kk + (lane >> 4) * 8]);
#pragma unroll
            for (int nt = 0; nt < 4; ++nt)
                bfr[nt] = *reinterpret_cast<const bf16x8*>(
                    &sB[wn + nt * 16 + (lane & 15)][kk + (lane >> 4) * 8]);
#pragma unroll
            for (int mt = 0; mt < 4; ++mt)
#pragma unroll
                for (int nt = 0; nt < 4; ++nt)
                    acc[mt][nt] = __builtin_amdgcn_mfma_f32_16x16x32_bf16(
                        af[mt], bfr[nt], acc[mt][nt], 0, 0, 0);
        }
    }

#pragma unroll
    for (int mt = 0; mt < 4; ++mt)
#pragma unroll
        for (int nt = 0; nt < 4; ++nt)
#pragma unroll
            for (int r = 0; r < 4; ++r) {
                int m = mt0 + wm + mt * 16 + (lane >> 4) * 4 + r;
                int j = nt0 + wn + nt * 16 + (lane & 15);
                float val = acc[mt][nt][r];
                if constexpr (MODE == 0) {
                    if (m < 512) {
                        qT[(((size_t)(b * H_ + (m >> 6)) * N_) + j) * D_ + (m & 63)] =
                            f2b(val * QSCALE);
                    } else if (m < 1024) {
                        int mm = m - 512;
                        kT[(((size_t)(b * H_ + (mm >> 6)) * N_) + j) * D_ + (mm & 63)] =
                            f2b(val);
                    } else {
                        int mm = m - 1024;
                        vv[(((size_t)(b * H_ + (mm >> 6)) * D_) + (mm & 63)) * N_ + j] =
                            f2b(val);
                    }
                } else {
                    out[((size_t)(b * C_ + m)) * N_ + j] = val + b_out[m];
                }
            }
}

// ---------------------------------------------------------------------------
// Attention v2: 128-row Q tile per block, 4 waves x 32 rows, zero barriers.
// - no max-tracking softmax (exp2 direct; q pre-scaled by log2e/8)
// - K/V MFMA fragments loaded straight from global (L1/L2-resident)
// - P bounced through XOR-swizzled LDS (wave-private rows)
// - deferred row-sum reduce (4 shuffles at the end)
// ---------------------------------------------------------------------------
__global__ __launch_bounds__(256) void k_attn(const ushort_t* __restrict__ qT,
                                              const ushort_t* __restrict__ kT,
                                              const ushort_t* __restrict__ vv,
                                              ushort_t* __restrict__ attnT) {
    // XCD-aware swizzle: 512 blocks, 8 XCDs -> 64 consecutive per XCD
    int sbid = ((blockIdx.x & 7) << 6) | (blockIdx.x >> 3);
    int it128 = sbid & 15;
    int h     = (sbid >> 4) & 7;
    int b     = sbid >> 7;
    int i0    = it128 * 128;
    int t = threadIdx.x, w = t >> 6, lane = t & 63;
    int low = lane & 15, hi = lane >> 4;

    __shared__ __align__(16) ushort_t sP[128][72];

    const ushort_t* qb = qT + ((size_t)(b * H_ + h)) * N_ * D_;
    const ushort_t* kb = kT + ((size_t)(b * H_ + h)) * N_ * D_;
    const ushort_t* vb = vv + ((size_t)(b * H_ + h)) * D_ * N_;

    // Q fragments in registers (wave w owns rows w*32 .. w*32+31)
    bf16x8 qf[2][2];
#pragma unroll
    for (int mt = 0; mt < 2; ++mt)
#pragma unroll
        for (int kx = 0; kx < 2; ++kx)
            qf[mt][kx] = *reinterpret_cast<const bf16x8*>(
                &qb[(size_t)(i0 + w * 32 + mt * 16 + low) * D_ + kx * 32 + hi * 8]);

    f32x4 oacc[2][4] = {};
    f32x4 lpart[2] = {};

    for (int jt = 0; jt < N_ / 64; ++jt) {
        int j0 = jt * 64;

        // S = Q K^T (rows: this wave's 32; cols: 64-wide KV tile)
        f32x4 sacc[2][4] = {};
#pragma unroll
        for (int kx = 0; kx < 2; ++kx) {
            bf16x8 kf[4];
#pragma unroll
            for (int nt = 0; nt < 4; ++nt)
                kf[nt] = *reinterpret_cast<const bf16x8*>(
                    &kb[(size_t)(j0 + nt * 16 + low) * D_ + kx * 32 + hi * 8]);
#pragma unroll
            for (int mt = 0; mt < 2; ++mt)
#pragma unroll
                for (int nt = 0; nt < 4; ++nt)
                    sacc[mt][nt] = __builtin_amdgcn_mfma_f32_16x16x32_bf16(
                        qf[mt][kx], kf[nt], sacc[mt][nt], 0, 0, 0);
        }

        // softmax numerator: P = exp2(S); accumulate per-lane row partial sums
#pragma unroll
        for (int mt = 0; mt < 2; ++mt) {
            int rowbase = w * 32 + mt * 16 + hi * 4;
#pragma unroll
            for (int nt = 0; nt < 4; ++nt) {
                int col = ((nt ^ hi) << 4) + low;   // XOR-swizzled 16-short block
                f32x4 p;
#pragma unroll
                for (int r = 0; r < 4; ++r)
                    p[r] = __builtin_amdgcn_exp2f(sacc[mt][nt][r]);
                lpart[mt] += p;
#pragma unroll
                for (int r = 0; r < 4; ++r)
                    sP[rowbase + r][col] = f2b(p[r]);
            }
        }

        // O += P V  (A-frags from swizzled sP, B-frags direct from global V)
#pragma unroll
        for (int kx = 0; kx < 2; ++kx) {
            bf16x8 ap[2];
#pragma unroll
            for (int mt = 0; mt < 2; ++mt) {
                int blk = ((kx * 2 + (hi >> 1)) ^ (low >> 2)) << 4;
                ap[mt] = *reinterpret_cast<const bf16x8*>(
                    &sP[w * 32 + mt * 16 + low][blk + (hi & 1) * 8]);
            }
#pragma unroll
            for (int dt = 0; dt < 4; ++dt) {
                bf16x8 bv = *reinterpret_cast<const bf16x8*>(
                    &vb[(size_t)(dt * 16 + low) * N_ + j0 + kx * 32 + hi * 8]);
#pragma unroll
                for (int mt = 0; mt < 2; ++mt)
                    oacc[mt][dt] = __builtin_amdgcn_mfma_f32_16x16x32_bf16(
                        ap[mt], bv, oacc[mt][dt], 0, 0, 0);
            }
        }
    }

    // finish row sums: reduce across the 16 lanes holding each row
    float linv[2][4];
#pragma unroll
    for (int mt = 0; mt < 2; ++mt)
#pragma unroll
        for (int r = 0; r < 4; ++r) {
            float s = lpart[mt][r];
            s += __shfl_xor(s, 1);
            s += __shfl_xor(s, 2);
            s += __shfl_xor(s, 4);
            s += __shfl_xor(s, 8);
            linv[mt][r] = 1.0f / s;
        }

    // normalize into sP (same swizzle), then 16B coalesced global stores
#pragma unroll
    for (int mt = 0; mt < 2; ++mt) {
        int rowbase = w * 32 + mt * 16 + hi * 4;
#pragma unroll
        for (int dt = 0; dt < 4; ++dt) {
            int col = ((dt ^ hi) << 4) + low;
#pragma unroll
            for (int r = 0; r < 4; ++r)
                sP[rowbase + r][col] = f2b(oacc[mt][dt][r] * linv[mt][r]);
        }
    }
    ushort_t* ob = attnT + ((size_t)(b * N_ + i0 + w * 32)) * C_ + h * D_;
#pragma unroll
    for (int c2 = 0; c2 < 4; ++c2) {
        int idx = c2 * 64 + lane;
        int rl  = idx >> 3;             // 0..31 local row
        int sub = idx & 7;              // 8-short subchunk
        int blk = ((sub >> 1) ^ ((rl >> 2) & 3)) << 4;
        uint4 vdata = *reinterpret_cast<const uint4*>(
            &sP[w * 32 + rl][blk + (sub & 1) * 8]);
        *reinterpret_cast<uint4*>(&ob[(size_t)rl * C_ + sub * 8]) = vdata;
    }
}

// ---------------------------------------------------------------------------
// Launch
// ---------------------------------------------------------------------------
extern "C" void kernel_launch(void* const* d_in, const int* in_sizes, int n_in,
                              void* d_out, int out_size, void* d_ws, size_t ws_size,
                              hipStream_t stream) {
    const float* x    = (const float*)d_in[0];
    const float* g    = (const float*)d_in[1];
    const float* wqkv = (const float*)d_in[2];
    const float* wout = (const float*)d_in[3];
    const float* bout = (const float*)d_in[4];
    float* out = (float*)d_out;

    char* ws = (char*)d_ws;
    ushort_t* xnT    = (ushort_t*)(ws);
    ushort_t* qT     = (ushort_t*)(ws + (size_t)8  * 1024 * 1024);
    ushort_t* kT     = (ushort_t*)(ws + (size_t)16 * 1024 * 1024);
    ushort_t* vv     = (ushort_t*)(ws + (size_t)24 * 1024 * 1024);
    ushort_t* attnT  = (ushort_t*)(ws + (size_t)32 * 1024 * 1024);
    ushort_t* wqkv_b = (ushort_t*)(ws + (size_t)40 * 1024 * 1024);
    ushort_t* wout_b = (ushort_t*)(ws + (size_t)42 * 1024 * 1024);

    k_cvt<<<dim3((O3_ * C_ + 255) / 256), dim3(256), 0, stream>>>(
        wqkv, wout, wqkv_b, wout_b);
    k_ln<<<dim3(B_ * (N_ / 32)), dim3(256), 0, stream>>>(x, g, xnT);
    k_gemm<0><<<dim3(B_ * (O3_ / 128) * (N_ / 128)), dim3(256), 0, stream>>>(
        wqkv_b, xnT, qT, kT, vv, nullptr, nullptr);
    k_attn<<<dim3(B_ * H_ * (N_ / 128)), dim3(256), 0, stream>>>(qT, kT, vv, attnT);
    k_gemm<1><<<dim3(B_ * (C_ / 128) * (N_ / 128)), dim3(256), 0, stream>>>(
        wout_b, attnT, nullptr, nullptr, nullptr, out, bout);
}